// Round 12
// baseline (116.978 us; speedup 1.0000x reference)
//
#include <hip/hip_runtime.h>
#include <hip/hip_fp16.h>
#include <math.h>

// Problem constants (fixed by setup_inputs)
#define B_   2
#define N_   256
#define P_   32
#define M_   16
#define C_   128
#define H_   256
#define NP_  (N_ * P_)          // 8192 points per batch
#define ROWS_ (B_ * NP_ * M_)   // 262144
#define TM_  64                 // rows per MLP chunk
#define LDA_ (H_ + 8)           // f16 leading dim pad
#define MROWS_ 1024             // rows per fused block (4 per thread)
#define MBLK_ (ROWS_ / MROWS_)  // 256 fused blocks (1 per CU)

typedef _Float16 half8 __attribute__((ext_vector_type(8)));
typedef float f32x4 __attribute__((ext_vector_type(4)));

// ---------------- prep kernel (R6-proven) -------------------------------------
// blocks 0..31 : LDS-tiled transpose W1/W2 -> Wt[n][k] f16
// blocks 32..63: cond = psf@Wc + bc + bp -> B0t rows; Wp -> B0t k=0..2
//   B0t layout: [b][h=256][k=32] f16. k=0..2: Wp^T; k=3+m: cond[b,m,:]+bp; k>=19: 0
__global__ __launch_bounds__(256)
void prep_k(const float* __restrict__ W1, const float* __restrict__ W2,
            _Float16* __restrict__ Wt1, _Float16* __restrict__ Wt2,
            const float* __restrict__ psf, const float* __restrict__ Wc,
            const float* __restrict__ bc, const float* __restrict__ Wp,
            const float* __restrict__ bp, _Float16* __restrict__ B0t) {
    __shared__ float t[64][65];
    const int tid = threadIdx.x;
    if (blockIdx.x < 32) {
        const int id = blockIdx.x;          // 2 mats x 16 tiles
        const float* W = (id & 1) ? W2 : W1;
        _Float16* Wt = (id & 1) ? Wt2 : Wt1;
        const int tile = id >> 1, I = tile >> 2, J = tile & 3;  // I: k-tile, J: n-tile
        const int r = tid >> 6, c = tid & 63;
        #pragma unroll
        for (int p = 0; p < 16; ++p)
            t[p * 4 + r][c] = W[(I * 64 + p * 4 + r) * H_ + J * 64 + c];
        __syncthreads();
        #pragma unroll
        for (int p = 0; p < 16; ++p)
            Wt[(J * 64 + p * 4 + r) * H_ + I * 64 + c] = (_Float16)t[c][p * 4 + r];
    } else {
        const int bm = blockIdx.x - 32;     // 0..31
        const int b = bm >> 4, m = bm & 15;
        const int h = tid;                  // 0..255
        const float* p = psf + bm * C_;
        float acc = bc[h];
        for (int c = 0; c < C_; ++c) acc += p[c] * Wc[c * H_ + h];
        _Float16* dst = B0t + (b * H_ + h) * 32;
        dst[3 + m] = (_Float16)(acc + bp[h]);
        if (m == 0) {
            dst[0] = (_Float16)Wp[h];
            dst[1] = (_Float16)Wp[H_ + h];
            dst[2] = (_Float16)Wp[2 * H_ + h];
            #pragma unroll
            for (int k = 19; k < 32; ++k) dst[k] = (_Float16)0.0f;
        }
    }
}

// ---------------- fused mask + MLP kernel -------------------------------------
// Block covers 1024 rows (64 points x 16 m), one batch half. Mask phase:
// fp32 contract-off F_ell (bit-identical to R6..R11); outside rows -> out=0
// (sigmoid(10*-100)==0.0f exactly); survivors -> LDS buffer (~42 expected).
// MLP phase: 64-row chunks over local survivors, straight from LDS — no
// global worklist, no global atomics, no memset node.
__global__ __launch_bounds__(256, 1)
void fused_k(const float* __restrict__ pts,  const float* __restrict__ trans,
             const float* __restrict__ rots, const float* __restrict__ scal,
             const float* __restrict__ b1v,  const float* __restrict__ b2v,
             const float* __restrict__ Wout, const float* __restrict__ bout,
             const _Float16* __restrict__ Wt1, const _Float16* __restrict__ Wt2,
             const _Float16* __restrict__ B0t, float* __restrict__ out) {
    __shared__ __align__(16) _Float16 sA0[TM_][32];     // [t0,t1,t2,onehot16,0..]
    __shared__ __align__(16) _Float16 sAbuf[TM_][LDA_]; // relu(net0), then relu(h1)
    __shared__ float sR[M_][9];
    __shared__ float sT[M_][3];
    __shared__ float sS[M_][3];
    __shared__ float sPart[TM_][4];
    __shared__ int   sBuf[MROWS_];
    __shared__ int   sCnt;

    const int tid  = threadIdx.x;
    const int base = blockIdx.x * MROWS_;
    const int b    = base >> 17;            // batch half

    if (tid == 0) sCnt = 0;
    if (tid < M_) {
        const int m = tid;
        const float* q = rots + (b * M_ + m) * 4;
        float w = q[0], x = q[1], y = q[2], z = q[3];
        float nrm = sqrtf(w * w + x * x + y * y + z * z);
        w /= nrm; x /= nrm; y /= nrm; z /= nrm;
        sR[m][0] = 1.0f - 2.0f * (y * y + z * z);
        sR[m][1] = 2.0f * (x * y - w * z);
        sR[m][2] = 2.0f * (x * z + w * y);
        sR[m][3] = 2.0f * (x * y + w * z);
        sR[m][4] = 1.0f - 2.0f * (x * x + z * z);
        sR[m][5] = 2.0f * (y * z - w * x);
        sR[m][6] = 2.0f * (x * z - w * y);
        sR[m][7] = 2.0f * (y * z + w * x);
        sR[m][8] = 1.0f - 2.0f * (x * x + y * y);
        const float* tp = trans + (b * M_ + m) * 3;
        sT[m][0] = tp[0]; sT[m][1] = tp[1]; sT[m][2] = tp[2];
        const float* sp = scal + (b * M_ + m) * 3;
        sS[m][0] = sp[0]; sS[m][1] = sp[1]; sS[m][2] = sp[2];
    }
    __syncthreads();

    // ---- mask phase: 4 rows per thread ----
    {
        const int m = tid & (M_ - 1);       // same m for all 4 rows of this thread
        #pragma unroll
        for (int r = 0; r < 4; ++r) {
            const int row = base + r * 256 + tid;
            const int gp  = row >> 4;       // global point index (b folded in)
            float fe;
            {
                #pragma clang fp contract(off)
                const float* p = pts + gp * 3;
                float x0 = p[0] - sT[m][0];
                float x1 = p[1] - sT[m][1];
                float x2 = p[2] - sT[m][2];
                float t0 = sR[m][0] * x0 + sR[m][1] * x1 + sR[m][2] * x2;
                float t1 = sR[m][3] * x0 + sR[m][4] * x1 + sR[m][5] * x2;
                float t2 = sR[m][6] * x0 + sR[m][7] * x1 + sR[m][8] * x2;
                float v0 = t0 / sS[m][0];
                float v1 = t1 / sS[m][1];
                float v2 = t2 / sS[m][2];
                fe = v0 * v0 + v1 * v1 + v2 * v2;
            }
            if (fe <= 1.0f) {
                const int pos = atomicAdd(&sCnt, 1);   // LDS atomic (per-CU, fast)
                sBuf[pos] = row;
            } else {
                out[row] = 0.0f;            // exact reference value outside mask
            }
        }
    }
    __syncthreads();
    const int count = sCnt;

    const int w    = tid >> 6;
    const int lane = tid & 63;
    const int quad = lane >> 4;
    const int ln   = lane & 15;
    const f32x4 zero = {0.0f, 0.0f, 0.0f, 0.0f};

    // ---- MLP phase: 64-row chunks over local survivors (usually 1 chunk) ----
    for (int off = 0; off < count; off += TM_) {
        // ---- stage A: build sA0 rows (f16) from gathered (point,m) ----
        {
            const int r  = tid >> 2;        // 0..63
            const int kg = tid & 3;         // 8-wide k chunk
            const int k  = off + r;
            const int idx  = (k < count) ? sBuf[k] : -1;
            const int safe = idx < 0 ? 0 : idx;
            const int m  = safe & (M_ - 1);
            const int gp = safe >> 4;
            half8 av;
            #pragma unroll
            for (int jj = 0; jj < 8; ++jj) av[jj] = (_Float16)0.0f;
            if (kg == 0) {
                float t0, t1, t2;
                {
                    #pragma clang fp contract(off)
                    const float* p = pts + gp * 3;
                    float x0 = p[0] - sT[m][0];
                    float x1 = p[1] - sT[m][1];
                    float x2 = p[2] - sT[m][2];
                    t0 = sR[m][0] * x0 + sR[m][1] * x1 + sR[m][2] * x2;
                    t1 = sR[m][3] * x0 + sR[m][4] * x1 + sR[m][5] * x2;
                    t2 = sR[m][6] * x0 + sR[m][7] * x1 + sR[m][8] * x2;
                }
                av[0] = (_Float16)t0; av[1] = (_Float16)t1; av[2] = (_Float16)t2;
                #pragma unroll
                for (int jj = 3; jj < 8; ++jj) av[jj] = (m == jj - 3) ? (_Float16)1.0f : (_Float16)0.0f;
            } else if (kg == 1) {           // k=8..15 -> m=5..12
                #pragma unroll
                for (int jj = 0; jj < 8; ++jj) av[jj] = (m == 5 + jj) ? (_Float16)1.0f : (_Float16)0.0f;
            } else if (kg == 2) {           // k=16..18 -> m=13..15
                #pragma unroll
                for (int jj = 0; jj < 3; ++jj) av[jj] = (m == 13 + jj) ? (_Float16)1.0f : (_Float16)0.0f;
            }
            *(half8*)&sA0[r][kg * 8] = av;
        }
        __syncthreads();

        // ---- GEMM 0: net0 = A0 @ B0 (K=32, cond+biases folded into B0) ----
        f32x4 acc0[4][4];
        {
            half8 a0[4], b0[4];
            #pragma unroll
            for (int rt = 0; rt < 4; ++rt)
                a0[rt] = *(const half8*)&sA0[rt * 16 + ln][quad * 8];
            const _Float16* B0w = B0t + (b * H_ + w * 64) * 32 + quad * 8;
            #pragma unroll
            for (int tc = 0; tc < 4; ++tc)
                b0[tc] = *(const half8*)(B0w + (tc * 16 + ln) * 32);
            #pragma unroll
            for (int rt = 0; rt < 4; ++rt)
                #pragma unroll
                for (int tc = 0; tc < 4; ++tc)
                    acc0[rt][tc] = __builtin_amdgcn_mfma_f32_16x16x32_f16(a0[rt], b0[tc], zero, 0, 0, 0);

            // ep0: relu(net0) -> sAbuf (acc0 keeps pre-relu net0 for the residual)
            #pragma unroll
            for (int tc = 0; tc < 4; ++tc) {
                const int col = w * 64 + tc * 16 + ln;
                #pragma unroll
                for (int rt = 0; rt < 4; ++rt)
                    #pragma unroll
                    for (int rg = 0; rg < 4; ++rg) {
                        float v = acc0[rt][tc][rg];
                        v = v > 0.0f ? v : 0.0f;
                        sAbuf[rt * 16 + quad * 4 + rg][col] = (_Float16)v;
                    }
            }
        }
        __syncthreads();

        // ---- GEMM 1: h1 = relu(net0) @ W1 + b1 ----
        f32x4 acc1[4][4];
        #pragma unroll
        for (int tc = 0; tc < 4; ++tc) {
            const float bb = b1v[w * 64 + tc * 16 + ln];
            const f32x4 bv = {bb, bb, bb, bb};
            #pragma unroll
            for (int rt = 0; rt < 4; ++rt) acc1[rt][tc] = bv;
        }
        {
            const _Float16* Wb1 = Wt1 + (w * 64) * H_;
            #pragma unroll
            for (int kc = 0; kc < 8; ++kc) {
                const int k0 = kc * 32 + quad * 8;
                half8 a[4], bf[4];
                #pragma unroll
                for (int rt = 0; rt < 4; ++rt)
                    a[rt] = *(const half8*)&sAbuf[rt * 16 + ln][k0];
                #pragma unroll
                for (int tc = 0; tc < 4; ++tc)
                    bf[tc] = *(const half8*)(Wb1 + (tc * 16 + ln) * H_ + k0);
                #pragma unroll
                for (int rt = 0; rt < 4; ++rt)
                    #pragma unroll
                    for (int tc = 0; tc < 4; ++tc)
                        acc1[rt][tc] = __builtin_amdgcn_mfma_f32_16x16x32_f16(a[rt], bf[tc], acc1[rt][tc], 0, 0, 0);
            }
        }
        __syncthreads();   // all GEMM1 reads of sAbuf complete before overwrite

        // ep1: relu(h1) -> sAbuf; acc1 dies here
        #pragma unroll
        for (int tc = 0; tc < 4; ++tc) {
            const int col = w * 64 + tc * 16 + ln;
            #pragma unroll
            for (int rt = 0; rt < 4; ++rt)
                #pragma unroll
                for (int rg = 0; rg < 4; ++rg) {
                    float v = acc1[rt][tc][rg];
                    v = v > 0.0f ? v : 0.0f;
                    sAbuf[rt * 16 + quad * 4 + rg][col] = (_Float16)v;
                }
        }
        __syncthreads();

        // ---- GEMM 2: net = net0 + b2 + relu(h1) @ W2 (accumulate into acc0) ----
        #pragma unroll
        for (int tc = 0; tc < 4; ++tc) {
            const float bb = b2v[w * 64 + tc * 16 + ln];
            const f32x4 bv = {bb, bb, bb, bb};
            #pragma unroll
            for (int rt = 0; rt < 4; ++rt) acc0[rt][tc] += bv;
        }
        {
            const _Float16* Wb2 = Wt2 + (w * 64) * H_;
            #pragma unroll
            for (int kc = 0; kc < 8; ++kc) {
                const int k0 = kc * 32 + quad * 8;
                half8 a[4], bf[4];
                #pragma unroll
                for (int rt = 0; rt < 4; ++rt)
                    a[rt] = *(const half8*)&sAbuf[rt * 16 + ln][k0];
                #pragma unroll
                for (int tc = 0; tc < 4; ++tc)
                    bf[tc] = *(const half8*)(Wb2 + (tc * 16 + ln) * H_ + k0);
                #pragma unroll
                for (int rt = 0; rt < 4; ++rt)
                    #pragma unroll
                    for (int tc = 0; tc < 4; ++tc)
                        acc0[rt][tc] = __builtin_amdgcn_mfma_f32_16x16x32_f16(a[rt], bf[tc], acc0[rt][tc], 0, 0, 0);
            }
        }

        // ep2: rowsum of relu(net)*Wout, reduce 16 lanes then cross-wave
        float rowsum[4][4];
        #pragma unroll
        for (int rt = 0; rt < 4; ++rt)
            #pragma unroll
            for (int rg = 0; rg < 4; ++rg) rowsum[rt][rg] = 0.0f;

        #pragma unroll
        for (int tc = 0; tc < 4; ++tc) {
            const float wo = Wout[w * 64 + tc * 16 + ln];
            #pragma unroll
            for (int rt = 0; rt < 4; ++rt)
                #pragma unroll
                for (int rg = 0; rg < 4; ++rg) {
                    float net = acc0[rt][tc][rg];
                    net = net > 0.0f ? net : 0.0f;
                    rowsum[rt][rg] += net * wo;
                }
        }

        #pragma unroll
        for (int rt = 0; rt < 4; ++rt)
            #pragma unroll
            for (int rg = 0; rg < 4; ++rg) {
                float v = rowsum[rt][rg];
                v += __shfl_xor(v, 1, 16);
                v += __shfl_xor(v, 2, 16);
                v += __shfl_xor(v, 4, 16);
                v += __shfl_xor(v, 8, 16);
                if (ln == 0) sPart[rt * 16 + quad * 4 + rg][w] = v;
            }
        __syncthreads();

        if (tid < TM_) {
            const int k = off + tid;
            if (k < count) {
                const int idx = sBuf[k];
                float occ = sPart[tid][0] + sPart[tid][1] + sPart[tid][2] + sPart[tid][3] + bout[0];
                out[idx] = 1.0f / (1.0f + __expf(-10.0f * occ));   // survivors inside mask
            }
        }
        __syncthreads();   // sPart/sAbuf reads done before next iter overwrites
    }
}

// ---------------- launch ------------------------------------------------------
extern "C" void kernel_launch(void* const* d_in, const int* in_sizes, int n_in,
                              void* d_out, int out_size, void* d_ws, size_t ws_size,
                              hipStream_t stream) {
    const float* pts   = (const float*)d_in[0];
    const float* trans = (const float*)d_in[1];
    const float* rots  = (const float*)d_in[2];
    const float* scal  = (const float*)d_in[3];
    const float* psf   = (const float*)d_in[4];
    const float* Wp    = (const float*)d_in[5];
    const float* bp    = (const float*)d_in[6];
    const float* Wc    = (const float*)d_in[7];
    const float* bc    = (const float*)d_in[8];
    const float* W1    = (const float*)d_in[9];
    const float* b1    = (const float*)d_in[10];
    const float* W2    = (const float*)d_in[11];
    const float* b2    = (const float*)d_in[12];
    const float* Wout  = (const float*)d_in[13];
    const float* bout  = (const float*)d_in[14];
    float* out = (float*)d_out;

    char* ws = (char*)d_ws;
    _Float16* Wt1 = (_Float16*)ws;                       // 131072 B ([n][k])
    _Float16* Wt2 = (_Float16*)(ws + 131072);            // 131072 B
    _Float16* B0t = (_Float16*)(ws + 262144);            // 32768 B

    hipLaunchKernelGGL(prep_k, dim3(64), dim3(256), 0, stream,
                       W1, W2, Wt1, Wt2, psf, Wc, bc, Wp, bp, B0t);
    hipLaunchKernelGGL(fused_k, dim3(MBLK_), dim3(256), 0, stream,
                       pts, trans, rots, scal, b1, b2, Wout, bout,
                       Wt1, Wt2, B0t, out);
}

// Round 13
// 104.779 us; speedup vs baseline: 1.1164x; 1.1164x over previous
//
#include <hip/hip_runtime.h>
#include <hip/hip_fp16.h>
#include <math.h>

// Problem constants (fixed by setup_inputs)
#define B_   2
#define N_   256
#define P_   32
#define M_   16
#define C_   128
#define H_   256
#define NP_  (N_ * P_)          // 8192 points per batch
#define ROWS_ (B_ * NP_ * M_)   // 262144
#define HALF_ (ROWS_ / 2)       // 131072 rows per batch
#define TM_  64                 // rows per pass-2 chunk
#define LDA_ (H_ + 8)           // f16 leading dim pad
#define MROWS_ 1024             // rows per mask block (4 per thread)
#define MBLK_ (ROWS_ / MROWS_)  // 256 mask blocks

typedef _Float16 half8 __attribute__((ext_vector_type(8)));
typedef float f32x4 __attribute__((ext_vector_type(4)));

// ---------------- pass 1: prep (blocks 0..63) + mask/compact (64..319) --------
// prep blocks 0..31 : LDS-tiled transpose W1/W2 -> Wt[n][k] f16
// prep blocks 32..63: cond = psf@Wc + bc + bp -> B0t rows; Wp -> B0t k=0..2
//   B0t layout: [b][h=256][k=32] f16. k=0..2: Wp^T; k=3+m: cond[b,m,:]+bp; k>=19: 0
// mask blocks: 1024 rows each. Survivors LDS-compacted; ONE global atomic per
//   block reserves a slice of the per-half worklist (dense -> balanced chunks
//   for pass 2); coalesced flush. Outside rows: out=0 written here directly
//   (sigmoid(10*-100)==0.0f exactly in fp32) -> no out-memset node needed.
//   Mask math fp32 contract-off — bit-identical to R6..R11 passing kernels.
__global__ __launch_bounds__(256)
void prep_mask_k(const float* __restrict__ W1, const float* __restrict__ W2,
                 _Float16* __restrict__ Wt1, _Float16* __restrict__ Wt2,
                 const float* __restrict__ psf, const float* __restrict__ Wc,
                 const float* __restrict__ bc, const float* __restrict__ Wp,
                 const float* __restrict__ bp, _Float16* __restrict__ B0t,
                 const float* __restrict__ pts, const float* __restrict__ trans,
                 const float* __restrict__ rots, const float* __restrict__ scal,
                 int* __restrict__ cnt, int* __restrict__ wl,
                 float* __restrict__ out) {
    __shared__ float t[64][65];
    const int tid = threadIdx.x;

    if (blockIdx.x < 32) {
        const int id = blockIdx.x;          // 2 mats x 16 tiles
        const float* W = (id & 1) ? W2 : W1;
        _Float16* Wt = (id & 1) ? Wt2 : Wt1;
        const int tile = id >> 1, I = tile >> 2, J = tile & 3;  // I: k-tile, J: n-tile
        const int r = tid >> 6, c = tid & 63;
        #pragma unroll
        for (int p = 0; p < 16; ++p)
            t[p * 4 + r][c] = W[(I * 64 + p * 4 + r) * H_ + J * 64 + c];
        __syncthreads();
        #pragma unroll
        for (int p = 0; p < 16; ++p)
            Wt[(J * 64 + p * 4 + r) * H_ + I * 64 + c] = (_Float16)t[c][p * 4 + r];
        return;
    }
    if (blockIdx.x < 64) {
        const int bm = blockIdx.x - 32;     // 0..31
        const int b = bm >> 4, m = bm & 15;
        const int h = tid;                  // 0..255
        const float* p = psf + bm * C_;
        float acc = bc[h];
        for (int c = 0; c < C_; ++c) acc += p[c] * Wc[c * H_ + h];
        _Float16* dst = B0t + (b * H_ + h) * 32;
        dst[3 + m] = (_Float16)(acc + bp[h]);
        if (m == 0) {
            dst[0] = (_Float16)Wp[h];
            dst[1] = (_Float16)Wp[H_ + h];
            dst[2] = (_Float16)Wp[2 * H_ + h];
            #pragma unroll
            for (int k = 19; k < 32; ++k) dst[k] = (_Float16)0.0f;
        }
        return;
    }

    // ---- mask part: block covers 1024 rows (64 points x 16 m), one b ----
    float (*sR)[9] = (float (*)[9])&t[0][0];          // reuse LDS
    float (*sT)[3] = (float (*)[3])&t[4][0];
    float (*sS)[3] = (float (*)[3])&t[8][0];
    __shared__ int sBuf[MROWS_];
    __shared__ int sCnt;
    __shared__ int sBase;

    const int base = (blockIdx.x - 64) * MROWS_;
    const int b    = base >> 17;

    if (tid == 0) sCnt = 0;
    if (tid < M_) {
        const int m = tid;
        const float* q = rots + (b * M_ + m) * 4;
        float w = q[0], x = q[1], y = q[2], z = q[3];
        float nrm = sqrtf(w * w + x * x + y * y + z * z);
        w /= nrm; x /= nrm; y /= nrm; z /= nrm;
        sR[m][0] = 1.0f - 2.0f * (y * y + z * z);
        sR[m][1] = 2.0f * (x * y - w * z);
        sR[m][2] = 2.0f * (x * z + w * y);
        sR[m][3] = 2.0f * (x * y + w * z);
        sR[m][4] = 1.0f - 2.0f * (x * x + z * z);
        sR[m][5] = 2.0f * (y * z - w * x);
        sR[m][6] = 2.0f * (x * z - w * y);
        sR[m][7] = 2.0f * (y * z + w * x);
        sR[m][8] = 1.0f - 2.0f * (x * x + y * y);
        const float* tp = trans + (b * M_ + m) * 3;
        sT[m][0] = tp[0]; sT[m][1] = tp[1]; sT[m][2] = tp[2];
        const float* sp = scal + (b * M_ + m) * 3;
        sS[m][0] = sp[0]; sS[m][1] = sp[1]; sS[m][2] = sp[2];
    }
    __syncthreads();

    const int m = tid & (M_ - 1);           // same m for all 4 rows of this thread
    #pragma unroll
    for (int r = 0; r < 4; ++r) {
        const int row = base + r * 256 + tid;
        const int gp  = row >> 4;           // global point index (b folded in)
        float fe;
        {
            #pragma clang fp contract(off)
            const float* p = pts + gp * 3;
            float x0 = p[0] - sT[m][0];
            float x1 = p[1] - sT[m][1];
            float x2 = p[2] - sT[m][2];
            float t0 = sR[m][0] * x0 + sR[m][1] * x1 + sR[m][2] * x2;
            float t1 = sR[m][3] * x0 + sR[m][4] * x1 + sR[m][5] * x2;
            float t2 = sR[m][6] * x0 + sR[m][7] * x1 + sR[m][8] * x2;
            float v0 = t0 / sS[m][0];
            float v1 = t1 / sS[m][1];
            float v2 = t2 / sS[m][2];
            fe = v0 * v0 + v1 * v1 + v2 * v2;
        }
        if (fe <= 1.0f) {
            const int pos = atomicAdd(&sCnt, 1);   // LDS atomic (per-CU, fast)
            sBuf[pos] = row;
        } else {
            out[row] = 0.0f;                // exact reference value outside mask
        }
    }
    __syncthreads();
    if (tid == 0) sBase = sCnt ? atomicAdd(&cnt[b], sCnt) : 0;  // 1 global atomic/blk
    __syncthreads();
    const int tot = sCnt, gb = b * HALF_ + sBase;
    for (int i = tid; i < tot; i += 256) wl[gb + i] = sBuf[i];  // coalesced flush
}

// ---------------- pass 2: MLP on surviving rows (R2-proven structure) ---------
// Dense per-half worklist -> every chunk is a full 64 rows; ~84 chunks/half ->
// 1 chunk/block, 1 block/CU. launch_bounds(256,1): waves/SIMD is 1 regardless
// (grid < CU count), so give the allocator the full VGPR file to hoist the
// weight-fragment loads — ILP is the only latency hiding available here.
__global__ __launch_bounds__(256, 1)
void occ_k(const float* __restrict__ pts,  const float* __restrict__ trans,
           const float* __restrict__ rots, const float* __restrict__ scal,
           const float* __restrict__ b1v,  const float* __restrict__ b2v,
           const float* __restrict__ Wout, const float* __restrict__ bout,
           const _Float16* __restrict__ Wt1, const _Float16* __restrict__ Wt2,
           const _Float16* __restrict__ B0t, const int* __restrict__ cnt,
           const int* __restrict__ wl, float* __restrict__ out) {
    const int half = blockIdx.x >> 8;       // grid 512: 256 chunk-slots per half
    const int j0   = blockIdx.x & 255;
    const int count = cnt[half];
    if (j0 * TM_ >= count) return;          // uniform early exit, before any barrier

    __shared__ __align__(16) _Float16 sA0[TM_][32];     // [t0,t1,t2,onehot16,0..]
    __shared__ __align__(16) _Float16 sAbuf[TM_][LDA_]; // relu(net0), then relu(h1)
    __shared__ float sR[M_][9];
    __shared__ float sT[M_][3];
    __shared__ float sS[M_][3];
    __shared__ float sPart[TM_][4];
    __shared__ int   sIdx[TM_];

    const int tid = threadIdx.x;
    const int b   = half;

    if (tid < M_) {
        const int m = tid;
        const float* q = rots + (b * M_ + m) * 4;
        float w = q[0], x = q[1], y = q[2], z = q[3];
        float nrm = sqrtf(w * w + x * x + y * y + z * z);
        w /= nrm; x /= nrm; y /= nrm; z /= nrm;
        sR[m][0] = 1.0f - 2.0f * (y * y + z * z);
        sR[m][1] = 2.0f * (x * y - w * z);
        sR[m][2] = 2.0f * (x * z + w * y);
        sR[m][3] = 2.0f * (x * y + w * z);
        sR[m][4] = 1.0f - 2.0f * (x * x + z * z);
        sR[m][5] = 2.0f * (y * z - w * x);
        sR[m][6] = 2.0f * (x * z - w * y);
        sR[m][7] = 2.0f * (y * z + w * x);
        sR[m][8] = 1.0f - 2.0f * (x * x + y * y);
        const float* tp = trans + (b * M_ + m) * 3;
        sT[m][0] = tp[0]; sT[m][1] = tp[1]; sT[m][2] = tp[2];
        const float* sp = scal + (b * M_ + m) * 3;
        sS[m][0] = sp[0]; sS[m][1] = sp[1]; sS[m][2] = sp[2];
    }

    const int w    = tid >> 6;
    const int lane = tid & 63;
    const int quad = lane >> 4;
    const int ln   = lane & 15;
    const f32x4 zero = {0.0f, 0.0f, 0.0f, 0.0f};

    for (int j = j0; j * TM_ < count; j += 256) {
        __syncthreads();   // prev iter's sIdx/sPart reads done; R/T/S ready (iter 0)
        if (tid < TM_) {
            const int k = j * TM_ + tid;
            sIdx[tid] = (k < count) ? wl[half * HALF_ + k] : -1;
        }
        __syncthreads();

        // ---- stage A: build sA0 rows (f16) from gathered (point,m) ----
        {
            const int r  = tid >> 2;        // 0..63
            const int kg = tid & 3;         // 8-wide k chunk
            const int idx  = sIdx[r];
            const int safe = idx < 0 ? 0 : idx;
            const int m  = safe & (M_ - 1);
            const int gp = safe >> 4;
            half8 av;
            #pragma unroll
            for (int jj = 0; jj < 8; ++jj) av[jj] = (_Float16)0.0f;
            if (kg == 0) {
                float t0, t1, t2;
                {
                    #pragma clang fp contract(off)
                    const float* p = pts + gp * 3;
                    float x0 = p[0] - sT[m][0];
                    float x1 = p[1] - sT[m][1];
                    float x2 = p[2] - sT[m][2];
                    t0 = sR[m][0] * x0 + sR[m][1] * x1 + sR[m][2] * x2;
                    t1 = sR[m][3] * x0 + sR[m][4] * x1 + sR[m][5] * x2;
                    t2 = sR[m][6] * x0 + sR[m][7] * x1 + sR[m][8] * x2;
                }
                av[0] = (_Float16)t0; av[1] = (_Float16)t1; av[2] = (_Float16)t2;
                #pragma unroll
                for (int jj = 3; jj < 8; ++jj) av[jj] = (m == jj - 3) ? (_Float16)1.0f : (_Float16)0.0f;
            } else if (kg == 1) {           // k=8..15 -> m=5..12
                #pragma unroll
                for (int jj = 0; jj < 8; ++jj) av[jj] = (m == 5 + jj) ? (_Float16)1.0f : (_Float16)0.0f;
            } else if (kg == 2) {           // k=16..18 -> m=13..15
                #pragma unroll
                for (int jj = 0; jj < 3; ++jj) av[jj] = (m == 13 + jj) ? (_Float16)1.0f : (_Float16)0.0f;
            }
            *(half8*)&sA0[r][kg * 8] = av;
        }
        __syncthreads();

        // ---- GEMM 0: net0 = A0 @ B0 (K=32, cond+biases folded into B0) ----
        f32x4 acc0[4][4];
        {
            half8 a0[4], b0[4];
            #pragma unroll
            for (int rt = 0; rt < 4; ++rt)
                a0[rt] = *(const half8*)&sA0[rt * 16 + ln][quad * 8];
            const _Float16* B0w = B0t + (b * H_ + w * 64) * 32 + quad * 8;
            #pragma unroll
            for (int tc = 0; tc < 4; ++tc)
                b0[tc] = *(const half8*)(B0w + (tc * 16 + ln) * 32);
            #pragma unroll
            for (int rt = 0; rt < 4; ++rt)
                #pragma unroll
                for (int tc = 0; tc < 4; ++tc)
                    acc0[rt][tc] = __builtin_amdgcn_mfma_f32_16x16x32_f16(a0[rt], b0[tc], zero, 0, 0, 0);

            // ep0: relu(net0) -> sAbuf (acc0 keeps pre-relu net0 for the residual)
            #pragma unroll
            for (int tc = 0; tc < 4; ++tc) {
                const int col = w * 64 + tc * 16 + ln;
                #pragma unroll
                for (int rt = 0; rt < 4; ++rt)
                    #pragma unroll
                    for (int rg = 0; rg < 4; ++rg) {
                        float v = acc0[rt][tc][rg];
                        v = v > 0.0f ? v : 0.0f;
                        sAbuf[rt * 16 + quad * 4 + rg][col] = (_Float16)v;
                    }
            }
        }
        __syncthreads();

        // ---- GEMM 1: h1 = relu(net0) @ W1 + b1 ----
        f32x4 acc1[4][4];
        #pragma unroll
        for (int tc = 0; tc < 4; ++tc) {
            const float bb = b1v[w * 64 + tc * 16 + ln];
            const f32x4 bv = {bb, bb, bb, bb};
            #pragma unroll
            for (int rt = 0; rt < 4; ++rt) acc1[rt][tc] = bv;
        }
        {
            const _Float16* Wb1 = Wt1 + (w * 64) * H_;
            #pragma unroll
            for (int kc = 0; kc < 8; ++kc) {
                const int k0 = kc * 32 + quad * 8;
                half8 a[4], bf[4];
                #pragma unroll
                for (int rt = 0; rt < 4; ++rt)
                    a[rt] = *(const half8*)&sAbuf[rt * 16 + ln][k0];
                #pragma unroll
                for (int tc = 0; tc < 4; ++tc)
                    bf[tc] = *(const half8*)(Wb1 + (tc * 16 + ln) * H_ + k0);
                #pragma unroll
                for (int rt = 0; rt < 4; ++rt)
                    #pragma unroll
                    for (int tc = 0; tc < 4; ++tc)
                        acc1[rt][tc] = __builtin_amdgcn_mfma_f32_16x16x32_f16(a[rt], bf[tc], acc1[rt][tc], 0, 0, 0);
            }
        }
        __syncthreads();   // all GEMM1 reads of sAbuf complete before overwrite

        // ep1: relu(h1) -> sAbuf; acc1 dies here
        #pragma unroll
        for (int tc = 0; tc < 4; ++tc) {
            const int col = w * 64 + tc * 16 + ln;
            #pragma unroll
            for (int rt = 0; rt < 4; ++rt)
                #pragma unroll
                for (int rg = 0; rg < 4; ++rg) {
                    float v = acc1[rt][tc][rg];
                    v = v > 0.0f ? v : 0.0f;
                    sAbuf[rt * 16 + quad * 4 + rg][col] = (_Float16)v;
                }
        }
        __syncthreads();

        // ---- GEMM 2: net = net0 + b2 + relu(h1) @ W2 (accumulate into acc0) ----
        #pragma unroll
        for (int tc = 0; tc < 4; ++tc) {
            const float bb = b2v[w * 64 + tc * 16 + ln];
            const f32x4 bv = {bb, bb, bb, bb};
            #pragma unroll
            for (int rt = 0; rt < 4; ++rt) acc0[rt][tc] += bv;
        }
        {
            const _Float16* Wb2 = Wt2 + (w * 64) * H_;
            #pragma unroll
            for (int kc = 0; kc < 8; ++kc) {
                const int k0 = kc * 32 + quad * 8;
                half8 a[4], bf[4];
                #pragma unroll
                for (int rt = 0; rt < 4; ++rt)
                    a[rt] = *(const half8*)&sAbuf[rt * 16 + ln][k0];
                #pragma unroll
                for (int tc = 0; tc < 4; ++tc)
                    bf[tc] = *(const half8*)(Wb2 + (tc * 16 + ln) * H_ + k0);
                #pragma unroll
                for (int rt = 0; rt < 4; ++rt)
                    #pragma unroll
                    for (int tc = 0; tc < 4; ++tc)
                        acc0[rt][tc] = __builtin_amdgcn_mfma_f32_16x16x32_f16(a[rt], bf[tc], acc0[rt][tc], 0, 0, 0);
            }
        }

        // ep2: rowsum of relu(net)*Wout, reduce 16 lanes then cross-wave
        float rowsum[4][4];
        #pragma unroll
        for (int rt = 0; rt < 4; ++rt)
            #pragma unroll
            for (int rg = 0; rg < 4; ++rg) rowsum[rt][rg] = 0.0f;

        #pragma unroll
        for (int tc = 0; tc < 4; ++tc) {
            const float wo = Wout[w * 64 + tc * 16 + ln];
            #pragma unroll
            for (int rt = 0; rt < 4; ++rt)
                #pragma unroll
                for (int rg = 0; rg < 4; ++rg) {
                    float net = acc0[rt][tc][rg];
                    net = net > 0.0f ? net : 0.0f;
                    rowsum[rt][rg] += net * wo;
                }
        }

        #pragma unroll
        for (int rt = 0; rt < 4; ++rt)
            #pragma unroll
            for (int rg = 0; rg < 4; ++rg) {
                float v = rowsum[rt][rg];
                v += __shfl_xor(v, 1, 16);
                v += __shfl_xor(v, 2, 16);
                v += __shfl_xor(v, 4, 16);
                v += __shfl_xor(v, 8, 16);
                if (ln == 0) sPart[rt * 16 + quad * 4 + rg][w] = v;
            }
        __syncthreads();

        if (tid < TM_) {
            const int idx = sIdx[tid];
            if (idx >= 0) {
                float occ = sPart[tid][0] + sPart[tid][1] + sPart[tid][2] + sPart[tid][3] + bout[0];
                out[idx] = 1.0f / (1.0f + __expf(-10.0f * occ));   // survivors inside mask
            }
        }
    }
}

// ---------------- launch ------------------------------------------------------
extern "C" void kernel_launch(void* const* d_in, const int* in_sizes, int n_in,
                              void* d_out, int out_size, void* d_ws, size_t ws_size,
                              hipStream_t stream) {
    const float* pts   = (const float*)d_in[0];
    const float* trans = (const float*)d_in[1];
    const float* rots  = (const float*)d_in[2];
    const float* scal  = (const float*)d_in[3];
    const float* psf   = (const float*)d_in[4];
    const float* Wp    = (const float*)d_in[5];
    const float* bp    = (const float*)d_in[6];
    const float* Wc    = (const float*)d_in[7];
    const float* bc    = (const float*)d_in[8];
    const float* W1    = (const float*)d_in[9];
    const float* b1    = (const float*)d_in[10];
    const float* W2    = (const float*)d_in[11];
    const float* b2    = (const float*)d_in[12];
    const float* Wout  = (const float*)d_in[13];
    const float* bout  = (const float*)d_in[14];
    float* out = (float*)d_out;

    char* ws = (char*)d_ws;
    _Float16* Wt1 = (_Float16*)ws;                       // 131072 B ([n][k])
    _Float16* Wt2 = (_Float16*)(ws + 131072);            // 131072 B
    _Float16* B0t = (_Float16*)(ws + 262144);            // 32768 B
    int*      cnt = (int*)(ws + 294912);                 // 8 B (2 counters)
    int*      wl  = (int*)(ws + 295168);                 // 2 x 131072 x 4 B

    hipMemsetAsync(cnt, 0, 2 * sizeof(int), stream);
    hipLaunchKernelGGL(prep_mask_k, dim3(64 + MBLK_), dim3(256), 0, stream,
                       W1, W2, Wt1, Wt2, psf, Wc, bc, Wp, bp, B0t,
                       pts, trans, rots, scal, cnt, wl, out);
    hipLaunchKernelGGL(occ_k, dim3(512), dim3(256), 0, stream,
                       pts, trans, rots, scal, b1, b2, Wout, bout,
                       Wt1, Wt2, B0t, cnt, wl, out);
}